// Round 3
// baseline (244.049 us; speedup 1.0000x reference)
//
#include <hip/hip_runtime.h>

#define SS 1024
#define GG 10
#define FF 5
#define BB 8
#define CC 3
#define KK (2 * FF + 1)

typedef float f32x4 __attribute__((ext_vector_type(4)));

// ---------------------------------------------------------------------------
// Kernel 1: smooth the (B,1,G,G) offset grids with an 11x11 gaussian
// (edge-padded), scale by max_offset, clip, store field [B][2][G][G] in ws.
// ---------------------------------------------------------------------------
__global__ __launch_bounds__(256) void rds_smooth_kernel(
    const float* __restrict__ ox, const float* __restrict__ oy,
    const float* __restrict__ w, const void* __restrict__ max_move_p,
    float* __restrict__ gs)
{
    int idx = blockIdx.x * 256 + threadIdx.x;
    if (idx >= BB * 2 * GG * GG) return;
    int j  = idx % GG;
    int i  = (idx / GG) % GG;
    int ch = (idx / (GG * GG)) % 2;
    int b  = idx / (2 * GG * GG);

    const float* o = (ch == 0 ? ox : oy) + b * GG * GG;

    // max_move: python scalar; hedge int32 vs float32 storage
    int mi = *(const int*)max_move_p;
    float mv = (mi >= -100000 && mi <= 100000) ? (float)mi : __int_as_float(mi);
    float max_offset = 2.0f * mv / (float)SS;

    float acc = 0.0f;
    for (int u = 0; u < KK; ++u) {
        int yy = min(max(i + u - FF, 0), GG - 1);
        for (int v = 0; v < KK; ++v) {
            int xx = min(max(j + v - FF, 0), GG - 1);
            acc += o[yy * GG + xx] * w[u * KK + v];
        }
    }
    acc *= max_offset;
    acc = fminf(fmaxf(acc, -max_offset), max_offset);
    gs[idx] = acc;
}

// ---------------------------------------------------------------------------
// Kernel 2: one block per (b,row); 256 threads x 4 px each = full 1024-px row.
// y-direction upsample interpolation hoisted to a 2x10 LDS row field (y is
// block-uniform). Per px: x-interp + base grid + clip + 4-corner gather of 3
// channels. float4 nontemporal stores.
// ---------------------------------------------------------------------------
__global__ __launch_bounds__(256) void rds_deform_kernel(
    const float* __restrict__ x, const float* __restrict__ gs,
    float* __restrict__ out)
{
    int bx  = blockIdx.x;            // grid = BB * SS
    int y   = bx & (SS - 1);
    int b   = bx >> 10;
    int tid = threadIdx.x;

    __shared__ float row0[GG];
    __shared__ float row1[GG];

    const float GdS = (float)GG / (float)SS;

    // y-direction upsample (uniform per block)
    float sy  = fmaxf(((float)y + 0.5f) * GdS - 0.5f, 0.0f);
    int   i0y = min((int)sy, GG - 1);      // sy >= 0 -> trunc == floor
    int   i1y = min(i0y + 1, GG - 1);
    float wyu = sy - (float)i0y;

    if (tid < 2 * GG) {
        int ch = tid / GG;
        int j  = tid - ch * GG;
        const float* gb = gs + (b * 2 + ch) * GG * GG;
        float v = gb[i0y * GG + j] * (1.0f - wyu) + gb[i1y * GG + j] * wyu;
        (ch ? row1 : row0)[j] = v;
    }
    __syncthreads();

    float py = (float)y * (2.0f / (float)(SS - 1)) - 1.0f;

    int   o00[4], o01[4], o10[4], o11[4];
    float w00[4], w01[4], w10[4], w11[4];

    #pragma unroll
    for (int p = 0; p < 4; ++p) {
        int xc = (tid << 2) + p;

        // x-direction upsample
        float sx  = fmaxf(((float)xc + 0.5f) * GdS - 0.5f, 0.0f);
        int   i0x = min((int)sx, GG - 1);
        int   i1x = min(i0x + 1, GG - 1);
        float wxu = sx - (float)i0x;

        float gxv = row0[i0x] + wxu * (row0[i1x] - row0[i0x]);
        float gyv = row1[i0x] + wxu * (row1[i1x] - row1[i0x]);

        float pxc = (float)xc * (2.0f / (float)(SS - 1)) - 1.0f;
        float gr0 = fminf(fmaxf(gxv + pxc, -1.0f), 1.0f);
        float gr1 = fminf(fmaxf(gyv + py,  -1.0f), 1.0f);

        // ((gr+1)*S-1)/2 == gr*512 + 511.5
        float ix = gr0 * 512.0f + 511.5f;
        float iy = gr1 * 512.0f + 511.5f;

        int   x0 = (int)floorf(ix);
        int   x1 = x0 + 1;
        int   y0 = (int)floorf(iy);
        int   y1 = y0 + 1;
        float wx = ix - (float)x0;
        float wy = iy - (float)y0;

        float mx0 = ((unsigned)x0 < (unsigned)SS) ? 1.0f : 0.0f;
        float mx1 = ((unsigned)x1 < (unsigned)SS) ? 1.0f : 0.0f;
        float my0 = ((unsigned)y0 < (unsigned)SS) ? 1.0f : 0.0f;
        float my1 = ((unsigned)y1 < (unsigned)SS) ? 1.0f : 0.0f;

        w00[p] = (1.0f - wy) * (1.0f - wx) * my0 * mx0;
        w01[p] = (1.0f - wy) * wx          * my0 * mx1;
        w10[p] = wy          * (1.0f - wx) * my1 * mx0;
        w11[p] = wy          * wx          * my1 * mx1;

        int cx0 = min(max(x0, 0), SS - 1);
        int cx1 = min(max(x1, 0), SS - 1);
        int cy0 = min(max(y0, 0), SS - 1);
        int cy1 = min(max(y1, 0), SS - 1);

        o00[p] = cy0 * SS + cx0;
        o01[p] = cy0 * SS + cx1;
        o10[p] = cy1 * SS + cx0;
        o11[p] = cy1 * SS + cx1;
    }

    const float* xb = x + (size_t)b * CC * SS * SS;
    size_t obase = (((size_t)b * CC) * SS + y) * SS + (tid << 2);

    #pragma unroll
    for (int c = 0; c < CC; ++c) {
        const float* img = xb + (size_t)c * SS * SS;
        float v[4];
        #pragma unroll
        for (int p = 0; p < 4; ++p) {
            v[p] = img[o00[p]] * w00[p] + img[o01[p]] * w01[p]
                 + img[o10[p]] * w10[p] + img[o11[p]] * w11[p];
        }
        f32x4 r = { v[0], v[1], v[2], v[3] };
        f32x4* op = (f32x4*)(out + obase + (size_t)c * SS * SS);
        __builtin_nontemporal_store(r, op);
    }
}

extern "C" void kernel_launch(void* const* d_in, const int* in_sizes, int n_in,
                              void* d_out, int out_size, void* d_ws, size_t ws_size,
                              hipStream_t stream) {
    const float* x        = (const float*)d_in[0];
    const float* offset_x = (const float*)d_in[1];
    const float* offset_y = (const float*)d_in[2];
    const float* weight   = (const float*)d_in[3];
    const void*  max_move = d_in[4];
    float* out = (float*)d_out;
    float* gs  = (float*)d_ws;   // [B][2][G][G] smoothed, scaled, clipped field

    int n1 = BB * 2 * GG * GG;   // 1600
    rds_smooth_kernel<<<(n1 + 255) / 256, 256, 0, stream>>>(
        offset_x, offset_y, weight, max_move, gs);

    int nblocks = BB * SS;       // one block per (batch,row)
    rds_deform_kernel<<<nblocks, 256, 0, stream>>>(x, gs, out);
}

// Round 4
// 203.438 us; speedup vs baseline: 1.1996x; 1.1996x over previous
//
#include <hip/hip_runtime.h>

#define SS 1024
#define GG 10
#define FF 5
#define BB 8
#define CC 3
#define KK (2 * FF + 1)

// ---------------------------------------------------------------------------
// Kernel 1: smooth the (B,1,G,G) offset grids with an 11x11 gaussian
// (edge-padded), scale by max_offset, clip, store field [B][2][G][G] in ws.
// ---------------------------------------------------------------------------
__global__ __launch_bounds__(256) void rds_smooth_kernel(
    const float* __restrict__ ox, const float* __restrict__ oy,
    const float* __restrict__ w, const void* __restrict__ max_move_p,
    float* __restrict__ gs)
{
    int idx = blockIdx.x * 256 + threadIdx.x;
    if (idx >= BB * 2 * GG * GG) return;
    int j  = idx % GG;
    int i  = (idx / GG) % GG;
    int ch = (idx / (GG * GG)) % 2;
    int b  = idx / (2 * GG * GG);

    const float* o = (ch == 0 ? ox : oy) + b * GG * GG;

    // max_move: python scalar; hedge int32 vs float32 storage
    int mi = *(const int*)max_move_p;
    float mv = (mi >= -100000 && mi <= 100000) ? (float)mi : __int_as_float(mi);
    float max_offset = 2.0f * mv / (float)SS;

    float acc = 0.0f;
    for (int u = 0; u < KK; ++u) {
        int yy = min(max(i + u - FF, 0), GG - 1);
        for (int v = 0; v < KK; ++v) {
            int xx = min(max(j + v - FF, 0), GG - 1);
            acc += o[yy * GG + xx] * w[u * KK + v];
        }
    }
    acc *= max_offset;
    acc = fminf(fmaxf(acc, -max_offset), max_offset);
    gs[idx] = acc;
}

// ---------------------------------------------------------------------------
// Kernel 2: one block per (b,row). 256 threads x 4 SEGMENTS (xc = tid+256*s)
// so every gather instruction keeps lane-stride 4B (fully coalesced), while
// each thread owns 48 independent corner loads for MLP. Explicit phases:
// address calc -> 48 loads -> FMAs -> stores. launch_bounds(256,4) allows
// up to 128 VGPRs so the loads actually stay in flight.
// ---------------------------------------------------------------------------
__global__ __launch_bounds__(256, 4) void rds_deform_kernel(
    const float* __restrict__ x, const float* __restrict__ gs,
    float* __restrict__ out)
{
    int bx  = blockIdx.x;            // grid = BB * SS
    int y   = bx & (SS - 1);
    int b   = bx >> 10;
    int tid = threadIdx.x;

    __shared__ float row0[GG];
    __shared__ float row1[GG];

    const float GdS = (float)GG / (float)SS;

    // y-direction upsample (uniform per block)
    float sy  = fmaxf(((float)y + 0.5f) * GdS - 0.5f, 0.0f);
    int   i0y = min((int)sy, GG - 1);      // sy >= 0 -> trunc == floor
    int   i1y = min(i0y + 1, GG - 1);
    float wyu = sy - (float)i0y;

    if (tid < 2 * GG) {
        int ch = tid / GG;
        int j  = tid - ch * GG;
        const float* gb = gs + (b * 2 + ch) * GG * GG;
        float v = gb[i0y * GG + j] * (1.0f - wyu) + gb[i1y * GG + j] * wyu;
        (ch ? row1 : row0)[j] = v;
    }
    __syncthreads();

    float py = (float)y * (2.0f / (float)(SS - 1)) - 1.0f;

    int   o00[4], o01[4], o10[4], o11[4];
    float w00[4], w01[4], w10[4], w11[4];

    // ---- phase 1: all address / weight math ----
    #pragma unroll
    for (int p = 0; p < 4; ++p) {
        int xc = tid + (p << 8);     // segment layout: lanes stay consecutive

        // x-direction upsample
        float sx  = fmaxf(((float)xc + 0.5f) * GdS - 0.5f, 0.0f);
        int   i0x = min((int)sx, GG - 1);
        int   i1x = min(i0x + 1, GG - 1);
        float wxu = sx - (float)i0x;

        float gxv = row0[i0x] + wxu * (row0[i1x] - row0[i0x]);
        float gyv = row1[i0x] + wxu * (row1[i1x] - row1[i0x]);

        float pxc = (float)xc * (2.0f / (float)(SS - 1)) - 1.0f;
        float gr0 = fminf(fmaxf(gxv + pxc, -1.0f), 1.0f);
        float gr1 = fminf(fmaxf(gyv + py,  -1.0f), 1.0f);

        // ((gr+1)*S-1)/2 == gr*512 + 511.5
        float ix = gr0 * 512.0f + 511.5f;
        float iy = gr1 * 512.0f + 511.5f;

        int   x0 = (int)floorf(ix);
        int   x1 = x0 + 1;
        int   y0 = (int)floorf(iy);
        int   y1 = y0 + 1;
        float wx = ix - (float)x0;
        float wy = iy - (float)y0;

        float mx0 = ((unsigned)x0 < (unsigned)SS) ? 1.0f : 0.0f;
        float mx1 = ((unsigned)x1 < (unsigned)SS) ? 1.0f : 0.0f;
        float my0 = ((unsigned)y0 < (unsigned)SS) ? 1.0f : 0.0f;
        float my1 = ((unsigned)y1 < (unsigned)SS) ? 1.0f : 0.0f;

        w00[p] = (1.0f - wy) * (1.0f - wx) * my0 * mx0;
        w01[p] = (1.0f - wy) * wx          * my0 * mx1;
        w10[p] = wy          * (1.0f - wx) * my1 * mx0;
        w11[p] = wy          * wx          * my1 * mx1;

        int cx0 = min(max(x0, 0), SS - 1);
        int cx1 = min(max(x1, 0), SS - 1);
        int cy0 = min(max(y0, 0), SS - 1);
        int cy1 = min(max(y1, 0), SS - 1);

        o00[p] = cy0 * SS + cx0;
        o01[p] = cy0 * SS + cx1;
        o10[p] = cy1 * SS + cx0;
        o11[p] = cy1 * SS + cx1;
    }

    const float* xb = x + (size_t)b * CC * SS * SS;

    // ---- phase 2: issue all 48 gathers ----
    float l00[CC * 4], l01[CC * 4], l10[CC * 4], l11[CC * 4];
    #pragma unroll
    for (int c = 0; c < CC; ++c) {
        const float* img = xb + (size_t)c * SS * SS;
        #pragma unroll
        for (int p = 0; p < 4; ++p) {
            l00[c * 4 + p] = img[o00[p]];
            l01[c * 4 + p] = img[o01[p]];
            l10[c * 4 + p] = img[o10[p]];
            l11[c * 4 + p] = img[o11[p]];
        }
    }

    // ---- phase 3: FMAs + coalesced stores ----
    size_t obase = (((size_t)b * CC) * SS + y) * SS + tid;
    #pragma unroll
    for (int c = 0; c < CC; ++c) {
        #pragma unroll
        for (int p = 0; p < 4; ++p) {
            float v = l00[c * 4 + p] * w00[p] + l01[c * 4 + p] * w01[p]
                    + l10[c * 4 + p] * w10[p] + l11[c * 4 + p] * w11[p];
            out[obase + (size_t)c * SS * SS + (size_t)(p << 8)] = v;
        }
    }
}

extern "C" void kernel_launch(void* const* d_in, const int* in_sizes, int n_in,
                              void* d_out, int out_size, void* d_ws, size_t ws_size,
                              hipStream_t stream) {
    const float* x        = (const float*)d_in[0];
    const float* offset_x = (const float*)d_in[1];
    const float* offset_y = (const float*)d_in[2];
    const float* weight   = (const float*)d_in[3];
    const void*  max_move = d_in[4];
    float* out = (float*)d_out;
    float* gs  = (float*)d_ws;   // [B][2][G][G] smoothed, scaled, clipped field

    int n1 = BB * 2 * GG * GG;   // 1600
    rds_smooth_kernel<<<(n1 + 255) / 256, 256, 0, stream>>>(
        offset_x, offset_y, weight, max_move, gs);

    int nblocks = BB * SS;       // one block per (batch,row)
    rds_deform_kernel<<<nblocks, 256, 0, stream>>>(x, gs, out);
}